// Round 5
// baseline (545.499 us; speedup 1.0000x reference)
//
#include <hip/hip_runtime.h>
#include <hip/hip_bf16.h>
#include <hip/hip_fp16.h>

#define IN_DIM 128
#define HID 64
#define BIN_BS 8192   // edges per bin batch (512 threads x 16)
#define BINB 512      // padded bucket-array width (>= B; N<=131072 -> B<=512)

typedef __hip_bfloat16 bf16;
typedef _Float16 fp16;
typedef _Float16 h2 __attribute__((ext_vector_type(2)));
typedef _Float16 f16x8 __attribute__((ext_vector_type(8)));
typedef float f32x4 __attribute__((ext_vector_type(4)));

// generic element load: is_f32 ? fp32 : bf16 (element-indexed)
__device__ __forceinline__ float loadf(const void* p, size_t i, int isf) {
    if (isf) return ((const float*)p)[i];
    unsigned int u = ((const unsigned short*)p)[i];
    union { unsigned int b; float f; } c;
    c.b = u << 16;
    return c.f;
}

__device__ __forceinline__ float bf2f(unsigned short u) {
    union { unsigned int b; float f; } c;
    c.b = ((unsigned int)u) << 16;
    return c.f;
}

// ---------------- dtype detector (flag=1 means fp32 buffers) ----------------
__global__ void detect_kernel(const unsigned short* __restrict__ feats, int* flag) {
    int lane = threadIdx.x;  // 64 threads
    int bad = 0;
    for (int j = lane; j < 128; j += 64) {
        unsigned short u = feats[j];
        int expo = (u >> 7) & 0xFF;
        if (expo >= 141) bad = 1;
    }
    unsigned long long m = __ballot(bad);
    if (lane == 0) *flag = (__popcll(m) > 4) ? 1 : 0;
}

// ---------------- init: zero deg_out + bucket cursors ----------------
__global__ void init_kernel(int* __restrict__ deg_out, int N,
                            int* __restrict__ gcursor, int B, int CAP) {
    int i = blockIdx.x * blockDim.x + threadIdx.x;
    int stride = gridDim.x * blockDim.x;
    for (int j = i; j < N; j += stride) deg_out[j] = 0;
    if (i < B) gcursor[i] = i * CAP;
}

// ---------------- edge binning by dst bucket (dst>>8), LDS-batched ----------------
__global__ __launch_bounds__(512) void bin_kernel(const int* __restrict__ src,
                                                  const int* __restrict__ dst,
                                                  int* __restrict__ deg_out,
                                                  int* __restrict__ gcursor,
                                                  int* __restrict__ binned,
                                                  int E, int sh, int nb) {
    __shared__ int scnt[BINB];    // per-bucket count, reused as rank counters
    __shared__ int sloff[BINB];   // exclusive batch-local offsets
    __shared__ int sgbase[BINB];  // per-bucket global base for this batch
    __shared__ int stage[BIN_BS];
    __shared__ int stotal;
    int tid = threadIdx.x;
    for (int batch = blockIdx.x; batch < nb; batch += gridDim.x) {
        int base = batch * BIN_BS;
        scnt[tid] = 0;
        __syncthreads();
        // phase 1: read edges (kept in regs), count buckets, deg_out atomics
        int ent[16], bk[16];
#pragma unroll
        for (int j = 0; j < 16; ++j) {
            int idx = base + tid + j * 512;
            bool ok = idx < E;
            int s = ok ? src[idx] : 0;
            int d = ok ? dst[idx] : 0;
            int b = d >> 8;
            bk[j] = ok ? b : -1;
            ent[j] = ((d & 255) << sh) | s;
            if (ok) {
                atomicAdd(&deg_out[s], 1);
                atomicAdd(&scnt[b], 1);
            }
        }
        __syncthreads();
        // phase 2: exclusive scan of per-bucket counts (Hillis-Steele, 512 wide)
        int c = scnt[tid];
        scnt[tid] = 0;  // reset for rank phase (own slot only - safe)
        sloff[tid] = c;
        __syncthreads();
        for (int off = 1; off < 512; off <<= 1) {
            int add = (tid >= off) ? sloff[tid - off] : 0;
            __syncthreads();
            sloff[tid] += add;
            __syncthreads();
        }
        int incl = sloff[tid];
        if (tid == 511) stotal = incl;
        sloff[tid] = incl - c;  // exclusive
        // phase 3: one global reservation per non-empty bucket
        if (c > 0) sgbase[tid] = atomicAdd(&gcursor[tid], c);
        __syncthreads();
        // phase 4: stage entries bucket-sorted in LDS
#pragma unroll
        for (int j = 0; j < 16; ++j) {
            int b = bk[j];
            if (b >= 0) {
                int r = atomicAdd(&scnt[b], 1);
                stage[sloff[b] + r] = ent[j];
            }
        }
        __syncthreads();
        // phase 5: coalesced flush; bucket of position i via binary search on sloff
        int tot = stotal;
        for (int i = tid; i < tot; i += 512) {
            int lo = 0, hi = BINB - 1;
            while (lo < hi) {
                int mid = (lo + hi + 1) >> 1;
                if (sloff[mid] <= i) lo = mid;
                else hi = mid - 1;
            }
            binned[sgbase[lo] + (i - sloff[lo])] = stage[i];
        }
        __syncthreads();  // protect LDS before next batch
    }
}

// ---------------- exclusive scan over bucket counts -> bucket output bases ----------------
__global__ __launch_bounds__(512) void bucket_scan_kernel(const int* __restrict__ gcursor,
                                                          int* __restrict__ bbase,
                                                          int* __restrict__ row_start,
                                                          int B, int CAP, int N) {
    __shared__ int part[512];
    int tid = threadIdx.x;
    int c = (tid < B) ? (gcursor[tid] - tid * CAP) : 0;
    part[tid] = c;
    __syncthreads();
    for (int off = 1; off < 512; off <<= 1) {
        int add = (tid >= off) ? part[tid - off] : 0;
        __syncthreads();
        part[tid] += add;
        __syncthreads();
    }
    if (tid < B) bbase[tid] = part[tid] - c;
    if (tid == 511) row_start[N] = part[511];  // == E
}

// ---------------- per-bucket CSR build: local degree count + scan + rank scatter ----
__global__ __launch_bounds__(256) void csr_build_kernel(const int* __restrict__ binned,
                                                        const int* __restrict__ gcursor,
                                                        const int* __restrict__ bbase,
                                                        int* __restrict__ row_start,
                                                        int* __restrict__ csr_src,
                                                        int N, int CAP, int sh) {
    __shared__ int lcnt[256];
    __shared__ int loff[256];
    int b = blockIdx.x;
    int tid = threadIdx.x;
    int rbase = b * CAP;
    int cnt = gcursor[b] - rbase;
    int obase = bbase[b];
    int n0 = b << 8;
    int mask = (1 << sh) - 1;
    lcnt[tid] = 0;
    __syncthreads();
    for (int i = tid; i < cnt; i += 256) {
        int e = binned[rbase + i];
        atomicAdd(&lcnt[e >> sh], 1);
    }
    __syncthreads();
    int c = lcnt[tid];
    lcnt[tid] = 0;  // reset for rank phase
    loff[tid] = c;
    __syncthreads();
    for (int off = 1; off < 256; off <<= 1) {
        int add = (tid >= off) ? loff[tid - off] : 0;
        __syncthreads();
        loff[tid] += add;
        __syncthreads();
    }
    int incl = loff[tid];
    loff[tid] = incl - c;  // exclusive
    if (n0 + tid < N) row_start[n0 + tid] = obase + incl - c;
    __syncthreads();
    for (int i = tid; i < cnt; i += 256) {
        int e = binned[rbase + i];
        int dl = e >> sh;
        int r = atomicAdd(&lcnt[dl], 1);
        csr_src[obase + loff[dl] + r] = e & mask;  // L2-localized scatter
    }
}

// ============ MFMA dense layer kernels ============
// mfma_f32_16x16x32_f16 fragment layouts (per guide, m89/m91-verified C/D):
//   A: lane holds A[row=lane&15][k = (lane>>4)*8 + j], j=0..7 (8 contiguous k)
//   B: lane holds B[k = (lane>>4)*8 + j][col=lane&15]  -> read from W^T, 8 contiguous k
//   C/D: col=lane&15, row=(lane>>4)*4 + reg

// ---------------- y1 = (x @ W1) * norm_src   [N,64] fp16, MFMA ----------------
__global__ __launch_bounds__(256) void xw1_mfma_kernel(const void* __restrict__ feats, size_t xoff,
                                                       const void* __restrict__ W1,
                                                       const int* __restrict__ deg_out,
                                                       const int* __restrict__ flag,
                                                       fp16* __restrict__ y1, int N) {
    __shared__ __align__(16) fp16 Wt[HID][IN_DIM + 8];  // [col][k] 17.4 KB
    int isf = *flag;
    int tid = threadIdx.x;
    for (int i = tid; i < IN_DIM * HID; i += 256) {
        int k = i >> 6, c = i & 63;
        Wt[c][k] = (fp16)loadf(W1, i, isf);
    }
    __syncthreads();
    int wave = tid >> 6, lane = tid & 63;
    int lr = lane & 15;        // A row / B col within tile
    int lk = (lane >> 4) * 8;  // k base within k-tile
    f16x8 bfr[4][4];
#pragma unroll
    for (int ct = 0; ct < 4; ++ct)
#pragma unroll
        for (int kt = 0; kt < 4; ++kt)
            bfr[ct][kt] = *(const f16x8*)&Wt[ct * 16 + lr][kt * 32 + lk];
    int tb = blockIdx.x * 64 + wave * 16;
    int rc = min(tb + lr, N - 1);
    f16x8 afr[4];
    if (isf) {
        const float* xr = (const float*)feats + xoff + (size_t)rc * IN_DIM + lk;
#pragma unroll
        for (int kt = 0; kt < 4; ++kt) {
            float4 p0 = *(const float4*)(xr + kt * 32);
            float4 p1 = *(const float4*)(xr + kt * 32 + 4);
            f16x8 a;
            a[0] = (fp16)p0.x; a[1] = (fp16)p0.y; a[2] = (fp16)p0.z; a[3] = (fp16)p0.w;
            a[4] = (fp16)p1.x; a[5] = (fp16)p1.y; a[6] = (fp16)p1.z; a[7] = (fp16)p1.w;
            afr[kt] = a;
        }
    } else {
        const unsigned short* xr = (const unsigned short*)feats + xoff + (size_t)rc * IN_DIM + lk;
#pragma unroll
        for (int kt = 0; kt < 4; ++kt) {
            uint4 q = *(const uint4*)(xr + kt * 32);
            f16x8 a;
            a[0] = (fp16)bf2f((unsigned short)(q.x & 0xffff));
            a[1] = (fp16)bf2f((unsigned short)(q.x >> 16));
            a[2] = (fp16)bf2f((unsigned short)(q.y & 0xffff));
            a[3] = (fp16)bf2f((unsigned short)(q.y >> 16));
            a[4] = (fp16)bf2f((unsigned short)(q.z & 0xffff));
            a[5] = (fp16)bf2f((unsigned short)(q.z >> 16));
            a[6] = (fp16)bf2f((unsigned short)(q.w & 0xffff));
            a[7] = (fp16)bf2f((unsigned short)(q.w >> 16));
            afr[kt] = a;
        }
    }
    f32x4 acc[4] = {};
#pragma unroll
    for (int ct = 0; ct < 4; ++ct)
#pragma unroll
        for (int kt = 0; kt < 4; ++kt)
            acc[ct] = __builtin_amdgcn_mfma_f32_16x16x32_f16(afr[kt], bfr[ct][kt], acc[ct], 0, 0, 0);
    int sr0 = tb + (lane >> 4) * 4;
    int sc = lane & 15;
#pragma unroll
    for (int i = 0; i < 4; ++i) {
        int row = sr0 + i;
        if (row < N) {
            float ns = rsqrtf(fmaxf((float)deg_out[row], 1.f));
#pragma unroll
            for (int ct = 0; ct < 4; ++ct)
                y1[(size_t)row * HID + ct * 16 + sc] = (fp16)(acc[ct][i] * ns);
        }
    }
}

// masked 16-deep gather for one node row; half-wave (32 lanes) per node, dword/lane.
__device__ __forceinline__ void half_gather(const fp16* __restrict__ y,
                                            const int* __restrict__ csr_src,
                                            int rs, int re, int sub,
                                            float& a0, float& a1) {
    for (int be = rs; be < re; be += 16) {
        int sarr[16];
#pragma unroll
        for (int j = 0; j < 16; ++j)
            sarr[j] = csr_src[min(be + j, re - 1)];  // clamp, safe addr
        unsigned uarr[16];
#pragma unroll
        for (int j = 0; j < 16; ++j)
            uarr[j] = ((const unsigned*)(y + (size_t)sarr[j] * HID))[sub];
#pragma unroll
        for (int j = 0; j < 16; ++j) {
            bool ok = be + j < re;
            h2 hh = __builtin_bit_cast(h2, uarr[j]);
            a0 += ok ? (float)hh[0] : 0.f;
            a1 += ok ? (float)hh[1] : 0.f;
        }
    }
}

// ---------------- FUSED: gather(y1)+relu -> LDS tile -> mlp2 MFMA -> y2 ----------------
// Block owns 64 dst nodes. Gather phase: 4 waves x 2 nodes (half-wave each) x 8 iters,
// results land in hh[64][36 dwords] (row stride 144B: 16B-aligned, half-wave writes
// conflict-free). One barrier, then the mlp2 MFMA reads A-fragments from LDS.
// Eliminates the hbuf HBM round-trip (25.6 MB) and overlaps gather latency with
// other blocks' MFMA phases.
__global__ __launch_bounds__(256, 4) void gmlp2_kernel(const fp16* __restrict__ y,
                                                       const void* __restrict__ bias,
                                                       const int* __restrict__ row_start,
                                                       const int* __restrict__ csr_src,
                                                       const void* __restrict__ W2,
                                                       const int* __restrict__ deg_out,
                                                       const int* __restrict__ flag,
                                                       fp16* __restrict__ y2, int N) {
    __shared__ __align__(16) fp16 Wt[HID][HID + 8];   // 9.2 KB
    __shared__ __align__(16) unsigned hh[64][36];     // 9.2 KB, gathered h tile
    int isf = *flag;
    int tid = threadIdx.x;
    for (int i = tid; i < HID * HID; i += 256) {
        int k = i >> 6, c = i & 63;
        Wt[c][k] = (fp16)loadf(W2, i, isf);
    }
    int wave = tid >> 6, lane = tid & 63, half = lane >> 5, sub = lane & 31;
    float bl0 = loadf(bias, 2 * sub, isf), bl1 = loadf(bias, 2 * sub + 1, isf);
    int base_n = blockIdx.x * 64;
    for (int it = 0; it < 8; ++it) {
        int slot = it * 8 + wave * 2 + half;
        int n = min(base_n + slot, N - 1);
        int rs = row_start[n], re = row_start[n + 1];
        float a0 = 0.f, a1 = 0.f;
        half_gather(y, csr_src, rs, re, sub, a0, a1);
        float nd = rsqrtf(fmaxf((float)(re - rs), 1.f));
        h2 rr;
        rr[0] = (fp16)fmaxf(fmaf(a0, nd, bl0), 0.f);  // relu (layer-1 activation)
        rr[1] = (fp16)fmaxf(fmaf(a1, nd, bl1), 0.f);
        hh[slot][sub] = __builtin_bit_cast(unsigned, rr);
    }
    __syncthreads();
    int lr = lane & 15, lk = (lane >> 4) * 8;
    f16x8 bfr[4][2];
#pragma unroll
    for (int ct = 0; ct < 4; ++ct)
#pragma unroll
        for (int kt = 0; kt < 2; ++kt)
            bfr[ct][kt] = *(const f16x8*)&Wt[ct * 16 + lr][kt * 32 + lk];
    f16x8 afr[2];
#pragma unroll
    for (int kt = 0; kt < 2; ++kt)
        afr[kt] = *(const f16x8*)&hh[wave * 16 + lr][kt * 16 + (lk >> 1)];
    f32x4 acc[4] = {};
#pragma unroll
    for (int ct = 0; ct < 4; ++ct)
#pragma unroll
        for (int kt = 0; kt < 2; ++kt)
            acc[ct] = __builtin_amdgcn_mfma_f32_16x16x32_f16(afr[kt], bfr[ct][kt], acc[ct], 0, 0, 0);
    int tb = base_n + wave * 16;
    int sr0 = tb + (lane >> 4) * 4;
    int sc = lane & 15;
#pragma unroll
    for (int i = 0; i < 4; ++i) {
        int row = sr0 + i;
        if (row < N) {
            float ns = rsqrtf(fmaxf((float)deg_out[row], 1.f));
#pragma unroll
            for (int ct = 0; ct < 4; ++ct)
                y2[(size_t)row * HID + ct * 16 + sc] = (fp16)(acc[ct][i] * ns);
        }
    }
}

// ---------------- FUSED: gather(y2) -> LDS tile -> mlp3 MFMA -> u, v ----------------
// Same structure, no relu, u/v halves computed sequentially to cap VGPR.
__global__ __launch_bounds__(256, 4) void gmlp3_kernel(const fp16* __restrict__ y,
                                                       const void* __restrict__ bias,
                                                       const int* __restrict__ row_start,
                                                       const int* __restrict__ csr_src,
                                                       const void* __restrict__ W3,
                                                       const int* __restrict__ flag,
                                                       fp16* __restrict__ u,
                                                       fp16* __restrict__ v, int N) {
    __shared__ __align__(16) fp16 Wt[HID][2 * HID + 8];  // 17.4 KB
    __shared__ __align__(16) unsigned hh[64][36];        // 9.2 KB
    int isf = *flag;
    int tid = threadIdx.x;
    for (int i = tid; i < 2 * HID * HID; i += 256) {
        int k = i >> 6, c = i & 63;  // k 0..127 (top then bottom half), c = out col
        Wt[c][k] = (fp16)loadf(W3, i, isf);
    }
    int wave = tid >> 6, lane = tid & 63, half = lane >> 5, sub = lane & 31;
    float bl0 = loadf(bias, 2 * sub, isf), bl1 = loadf(bias, 2 * sub + 1, isf);
    int base_n = blockIdx.x * 64;
    for (int it = 0; it < 8; ++it) {
        int slot = it * 8 + wave * 2 + half;
        int n = min(base_n + slot, N - 1);
        int rs = row_start[n], re = row_start[n + 1];
        float a0 = 0.f, a1 = 0.f;
        half_gather(y, csr_src, rs, re, sub, a0, a1);
        float nd = rsqrtf(fmaxf((float)(re - rs), 1.f));
        h2 rr;
        rr[0] = (fp16)fmaf(a0, nd, bl0);  // no relu (layer-2 output)
        rr[1] = (fp16)fmaf(a1, nd, bl1);
        hh[slot][sub] = __builtin_bit_cast(unsigned, rr);
    }
    __syncthreads();
    int lr = lane & 15, lk = (lane >> 4) * 8;
    f16x8 afr[2];
#pragma unroll
    for (int kt = 0; kt < 2; ++kt)
        afr[kt] = *(const f16x8*)&hh[wave * 16 + lr][kt * 16 + (lk >> 1)];
    int tb = base_n + wave * 16;
    int sr0 = tb + (lane >> 4) * 4;
    int sc = lane & 15;
    // ---- u half ----
    {
        f16x8 bu[4][2];
#pragma unroll
        for (int ct = 0; ct < 4; ++ct)
#pragma unroll
            for (int kt = 0; kt < 2; ++kt)
                bu[ct][kt] = *(const f16x8*)&Wt[ct * 16 + lr][kt * 32 + lk];
        f32x4 accu[4] = {};
#pragma unroll
        for (int ct = 0; ct < 4; ++ct)
#pragma unroll
            for (int kt = 0; kt < 2; ++kt)
                accu[ct] = __builtin_amdgcn_mfma_f32_16x16x32_f16(afr[kt], bu[ct][kt], accu[ct], 0, 0, 0);
#pragma unroll
        for (int i = 0; i < 4; ++i) {
            int row = sr0 + i;
            if (row < N) {
#pragma unroll
                for (int ct = 0; ct < 4; ++ct)
                    u[(size_t)row * HID + ct * 16 + sc] = (fp16)accu[ct][i];
            }
        }
    }
    // ---- v half ----
    {
        f16x8 bv[4][2];
#pragma unroll
        for (int ct = 0; ct < 4; ++ct)
#pragma unroll
            for (int kt = 0; kt < 2; ++kt)
                bv[ct][kt] = *(const f16x8*)&Wt[ct * 16 + lr][HID + kt * 32 + lk];
        f32x4 accv[4] = {};
#pragma unroll
        for (int ct = 0; ct < 4; ++ct)
#pragma unroll
            for (int kt = 0; kt < 2; ++kt)
                accv[ct] = __builtin_amdgcn_mfma_f32_16x16x32_f16(afr[kt], bv[ct][kt], accv[ct], 0, 0, 0);
#pragma unroll
        for (int i = 0; i < 4; ++i) {
            int row = sr0 + i;
            if (row < N) {
#pragma unroll
                for (int ct = 0; ct < 4; ++ct)
                    v[(size_t)row * HID + ct * 16 + sc] = (fp16)accv[ct][i];
            }
        }
    }
}

// ---------------- per-edge scorer, 2 edges/wave packed, 8 pairs in flight ----
#define SCORE_U 8
__global__ __launch_bounds__(256, 8) void score_kernel(const fp16* __restrict__ u,
                                                       const fp16* __restrict__ v,
                                                       const int* __restrict__ sn,
                                                       const int* __restrict__ dn,
                                                       const void* __restrict__ b3,
                                                       const void* __restrict__ W4,
                                                       const void* __restrict__ b4,
                                                       const int* __restrict__ flag,
                                                       void* __restrict__ out, int E) {
    int isf = *flag;
    int tid = threadIdx.x;
    int lane = tid & 63;
    int half = lane >> 5, sub = lane & 31;
    int gw = (blockIdx.x * 256 + tid) >> 6;  // global wave id
    int nw = gridDim.x * 4;
    float b30 = loadf(b3, 2 * sub, isf), b31 = loadf(b3, 2 * sub + 1, isf);
    float w40 = loadf(W4, 2 * sub, isf), w41 = loadf(W4, 2 * sub + 1, isf);
    float b4v = loadf(b4, 0, isf);
    const int P = (E + 1) >> 1;  // pairs

    int p0 = gw;
    for (; p0 + (SCORE_U - 1) * nw < P - 1; p0 += SCORE_U * nw) {
        int ss[SCORE_U], dd[SCORE_U];
#pragma unroll
        for (int j = 0; j < SCORE_U; ++j) {
            int e = 2 * (p0 + j * nw) + half;
            ss[j] = sn[e];
            dd[j] = dn[e];
        }
        unsigned pu[SCORE_U], pv[SCORE_U];
#pragma unroll
        for (int j = 0; j < SCORE_U; ++j) {
            pu[j] = ((const unsigned*)(u + (size_t)ss[j] * HID))[sub];
            pv[j] = ((const unsigned*)(v + (size_t)dd[j] * HID))[sub];
        }
#pragma unroll
        for (int j = 0; j < SCORE_U; ++j) {
            int e = 2 * (p0 + j * nw) + half;
            h2 hu = __builtin_bit_cast(h2, pu[j]);
            h2 hv = __builtin_bit_cast(h2, pv[j]);
            float h0 = fmaxf((float)hu[0] + (float)hv[0] + b30, 0.f);
            float h1 = fmaxf((float)hu[1] + (float)hv[1] + b31, 0.f);
            float pp = fmaf(h0, w40, h1 * w41);
#pragma unroll
            for (int off = 16; off > 0; off >>= 1) pp += __shfl_xor(pp, off, 64);
            if (sub == 0) {
                float r = pp + b4v;
                if (isf) ((float*)out)[e] = r;
                else     ((bf16*)out)[e] = __float2bfloat16(r);
            }
        }
    }
    // guarded tail
    for (; p0 < P; p0 += nw) {
        int e = 2 * p0 + half;
        int ec = min(e, E - 1);
        int s = sn[ec], d = dn[ec];
        unsigned pu = ((const unsigned*)(u + (size_t)s * HID))[sub];
        unsigned pv = ((const unsigned*)(v + (size_t)d * HID))[sub];
        h2 hu = __builtin_bit_cast(h2, pu);
        h2 hv = __builtin_bit_cast(h2, pv);
        float h0 = fmaxf((float)hu[0] + (float)hv[0] + b30, 0.f);
        float h1 = fmaxf((float)hu[1] + (float)hv[1] + b31, 0.f);
        float pp = fmaf(h0, w40, h1 * w41);
#pragma unroll
        for (int off = 16; off > 0; off >>= 1) pp += __shfl_xor(pp, off, 64);
        if (sub == 0 && e < E) {
            float r = pp + b4v;
            if (isf) ((float*)out)[e] = r;
            else     ((bf16*)out)[e] = __float2bfloat16(r);
        }
    }
}

extern "C" void kernel_launch(void* const* d_in, const int* in_sizes, int n_in,
                              void* d_out, int out_size, void* d_ws, size_t ws_size,
                              hipStream_t stream) {
    const void* feats = d_in[0];
    const void* W1 = d_in[1];
    const void* b1 = d_in[2];
    const void* W2 = d_in[3];
    const void* b2 = d_in[4];
    const void* W3 = d_in[5];
    const void* b3 = d_in[6];
    const void* W4 = d_in[7];
    const void* b4 = d_in[8];
    const int* src_seq = (const int*)d_in[9];
    const int* dst_seq = (const int*)d_in[10];
    const int* src_next = (const int*)d_in[11];
    const int* dst_next = (const int*)d_in[12];

    const int E = in_sizes[11];                // src_next
    const int N = in_sizes[0] / (3 * IN_DIM);  // feats = [T=3, N, 128]
    const int T = in_sizes[9] / E;             // 3

    // only the last snapshot matters: h = h_seq[-1]
    const size_t xoff = (size_t)(T - 1) * N * IN_DIM;  // element offset into feats
    const int* src = src_seq + (size_t)(T - 1) * E;
    const int* dst = dst_seq + (size_t)(T - 1) * E;

    char* w = (char*)d_ws;
    auto alloc = [&](size_t bytes) {
        void* p = (void*)w;
        w += (bytes + 255) & ~(size_t)255;
        return p;
    };
    int* flag      = (int*)alloc(4);
    int* deg_out   = (int*)alloc((size_t)N * 4);
    int* row_start = (int*)alloc((size_t)(N + 1) * 4);
    int* gcursor   = (int*)alloc(512 * 4);
    int* bbase     = (int*)alloc(512 * 4);
    int* csr_src   = (int*)alloc((size_t)E * 4);
    fp16* y1       = (fp16*)alloc((size_t)N * HID * 2);
    fp16* y2       = (fp16*)alloc((size_t)N * HID * 2);
    fp16* vv       = (fp16*)alloc((size_t)N * HID * 2);
    fp16* uu       = y1;         // y1 dead after gmlp2's gather; reuse as u
    int* binned    = (int*)y2;   // y2 first written by gmlp2 (after csr_build) -> safe alias

    // bucket geometry: 256 dst nodes per bucket
    const int B = (N + 255) >> 8;              // 391 for N=100K (must be <=512)
    int sh = 1;
    while ((1 << sh) < N) ++sh;                // 17 bits for src
    int avg = (E + B - 1) / B;
    int CAP = (avg + avg / 2 + 256 + 15) & ~15;  // ~+50% headroom over mean degree*256
    size_t maxints = (size_t)N * HID * 2 / 4;    // ints available in y2 alias
    if ((size_t)B * CAP > maxints) CAP = (int)(maxints / B) & ~15;
    const int nb = (E + BIN_BS - 1) / BIN_BS;  // 196 batches
    const int GB = (N + 63) / 64;              // per-64-node grids

    detect_kernel<<<1, 64, 0, stream>>>((const unsigned short*)feats, flag);
    init_kernel<<<512, 256, 0, stream>>>(deg_out, N, gcursor, B, CAP);
    // CSR build: bin by dst bucket (coalesced), then per-bucket L2-local scatter
    bin_kernel<<<nb, 512, 0, stream>>>(src, dst, deg_out, gcursor, binned, E, sh, nb);
    bucket_scan_kernel<<<1, 512, 0, stream>>>(gcursor, bbase, row_start, B, CAP, N);
    csr_build_kernel<<<B, 256, 0, stream>>>(binned, gcursor, bbase, row_start, csr_src,
                                            N, CAP, sh);
    xw1_mfma_kernel<<<GB, 256, 0, stream>>>(feats, xoff, W1, deg_out, flag, y1, N);
    // fused layer 1: gather(y1)+relu -> mlp2 -> y2   (no hbuf round-trip)
    gmlp2_kernel<<<GB, 256, 0, stream>>>(y1, b1, row_start, csr_src, W2, deg_out, flag, y2, N);
    // fused layer 2: gather(y2) -> mlp3 -> u, v
    gmlp3_kernel<<<GB, 256, 0, stream>>>(y2, b2, row_start, csr_src, W3, flag, uu, vv, N);
    score_kernel<<<4096, 256, 0, stream>>>(uu, vv, src_next, dst_next, b3, W4, b4, flag,
                                           (void*)d_out, E);
}

// Round 6
// 533.868 us; speedup vs baseline: 1.0218x; 1.0218x over previous
//
#include <hip/hip_runtime.h>
#include <hip/hip_bf16.h>
#include <hip/hip_fp16.h>

#define IN_DIM 128
#define HID 64
#define BIN_BS 8192   // edges per bin batch (512 threads x 16)
#define BINB 512      // padded bucket-array width (>= B; N<=131072 -> B<=512)

typedef __hip_bfloat16 bf16;
typedef _Float16 fp16;
typedef _Float16 h2 __attribute__((ext_vector_type(2)));
typedef _Float16 f16x8 __attribute__((ext_vector_type(8)));
typedef float f32x4 __attribute__((ext_vector_type(4)));

// generic element load: is_f32 ? fp32 : bf16 (element-indexed)
__device__ __forceinline__ float loadf(const void* p, size_t i, int isf) {
    if (isf) return ((const float*)p)[i];
    unsigned int u = ((const unsigned short*)p)[i];
    union { unsigned int b; float f; } c;
    c.b = u << 16;
    return c.f;
}

__device__ __forceinline__ float bf2f(unsigned short u) {
    union { unsigned int b; float f; } c;
    c.b = ((unsigned int)u) << 16;
    return c.f;
}

// ---------------- init: dtype detect + zero deg_out + bucket cursors ----------------
__global__ void init_kernel(const unsigned short* __restrict__ feats, int* flag,
                            int* __restrict__ deg_out, int N,
                            int* __restrict__ gcursor, int B, int CAP) {
    int i = blockIdx.x * blockDim.x + threadIdx.x;
    int stride = gridDim.x * blockDim.x;
    for (int j = i; j < N; j += stride) deg_out[j] = 0;
    if (i < B) gcursor[i] = i * CAP;
    if (blockIdx.x == 0 && threadIdx.x < 64) {  // wave 0 does the dtype sniff
        int lane = threadIdx.x;
        int bad = 0;
        for (int j = lane; j < 128; j += 64) {
            unsigned short u = feats[j];
            int expo = (u >> 7) & 0xFF;
            if (expo >= 141) bad = 1;
        }
        unsigned long long m = __ballot(bad);
        if (lane == 0) *flag = (__popcll(m) > 4) ? 1 : 0;
    }
}

// ---------------- edge binning by dst bucket (dst>>8), direct rank-scatter ----------
// Intra-bucket order is irrelevant (csr_build re-sorts), so no staging/scan/search:
// count -> one global reservation per non-empty bucket -> atomic-rank scatter.
// 4 barriers + 4KB LDS vs the old 22-barrier/40KB staged version. Scattered 4B
// writes land in same-block ~84B bucket runs -> coalesced at L2 write-back.
__global__ __launch_bounds__(512) void bin_kernel(const int* __restrict__ src,
                                                  const int* __restrict__ dst,
                                                  int* __restrict__ deg_out,
                                                  int* __restrict__ gcursor,
                                                  int* __restrict__ binned,
                                                  int E, int sh, int nb) {
    __shared__ int scnt[BINB];    // per-bucket count, then rank counters
    __shared__ int sgbase[BINB];  // per-bucket global base for this batch
    int tid = threadIdx.x;
    for (int batch = blockIdx.x; batch < nb; batch += gridDim.x) {
        int base = batch * BIN_BS;
        scnt[tid] = 0;
        __syncthreads();
        // phase 1: read edges (kept in regs), count buckets, deg_out atomics
        int ent[16], bk[16];
#pragma unroll
        for (int j = 0; j < 16; ++j) {
            int idx = base + tid + j * 512;
            bool ok = idx < E;
            int s = ok ? src[idx] : 0;
            int d = ok ? dst[idx] : 0;
            int b = d >> 8;
            bk[j] = ok ? b : -1;
            ent[j] = ((d & 255) << sh) | s;
            if (ok) {
                atomicAdd(&deg_out[s], 1);
                atomicAdd(&scnt[b], 1);
            }
        }
        __syncthreads();
        // phase 2: one global reservation per non-empty bucket
        int c = scnt[tid];
        if (c > 0) sgbase[tid] = atomicAdd(&gcursor[tid], c);
        __syncthreads();
        scnt[tid] = 0;  // reuse as rank counters
        __syncthreads();
        // phase 3: direct rank scatter
#pragma unroll
        for (int j = 0; j < 16; ++j) {
            int b = bk[j];
            if (b >= 0) {
                int r = atomicAdd(&scnt[b], 1);
                binned[sgbase[b] + r] = ent[j];
            }
        }
        __syncthreads();  // protect scnt before next batch
    }
}

// ---------------- exclusive scan over bucket counts -> bucket output bases ----------------
__global__ __launch_bounds__(512) void bucket_scan_kernel(const int* __restrict__ gcursor,
                                                          int* __restrict__ bbase,
                                                          int* __restrict__ row_start,
                                                          int B, int CAP, int N) {
    __shared__ int part[512];
    int tid = threadIdx.x;
    int c = (tid < B) ? (gcursor[tid] - tid * CAP) : 0;
    part[tid] = c;
    __syncthreads();
    for (int off = 1; off < 512; off <<= 1) {
        int add = (tid >= off) ? part[tid - off] : 0;
        __syncthreads();
        part[tid] += add;
        __syncthreads();
    }
    if (tid < B) bbase[tid] = part[tid] - c;
    if (tid == 511) row_start[N] = part[511];  // == E
}

// ---------------- per-bucket CSR build: local degree count + scan + rank scatter ----
__global__ __launch_bounds__(256) void csr_build_kernel(const int* __restrict__ binned,
                                                        const int* __restrict__ gcursor,
                                                        const int* __restrict__ bbase,
                                                        int* __restrict__ row_start,
                                                        int* __restrict__ csr_src,
                                                        int N, int CAP, int sh) {
    __shared__ int lcnt[256];
    __shared__ int loff[256];
    int b = blockIdx.x;
    int tid = threadIdx.x;
    int rbase = b * CAP;
    int cnt = gcursor[b] - rbase;
    int obase = bbase[b];
    int n0 = b << 8;
    int mask = (1 << sh) - 1;
    lcnt[tid] = 0;
    __syncthreads();
    for (int i = tid; i < cnt; i += 256) {
        int e = binned[rbase + i];
        atomicAdd(&lcnt[e >> sh], 1);
    }
    __syncthreads();
    int c = lcnt[tid];
    lcnt[tid] = 0;  // reset for rank phase
    loff[tid] = c;
    __syncthreads();
    for (int off = 1; off < 256; off <<= 1) {
        int add = (tid >= off) ? loff[tid - off] : 0;
        __syncthreads();
        loff[tid] += add;
        __syncthreads();
    }
    int incl = loff[tid];
    loff[tid] = incl - c;  // exclusive
    if (n0 + tid < N) row_start[n0 + tid] = obase + incl - c;
    __syncthreads();
    for (int i = tid; i < cnt; i += 256) {
        int e = binned[rbase + i];
        int dl = e >> sh;
        int r = atomicAdd(&lcnt[dl], 1);
        csr_src[obase + loff[dl] + r] = e & mask;  // L2-localized scatter
    }
}

// ============ MFMA dense layer kernels ============
// mfma_f32_16x16x32_f16 fragment layouts (per guide, m89/m91-verified C/D):
//   A: lane holds A[row=lane&15][k = (lane>>4)*8 + j], j=0..7 (8 contiguous k)
//   B: lane holds B[k = (lane>>4)*8 + j][col=lane&15]  -> read from W^T, 8 contiguous k
//   C/D: col=lane&15, row=(lane>>4)*4 + reg
// 64 rows per block -> ~1563 blocks (6/CU) so the memory pipes fill.

// ---------------- y1 = (x @ W1) * norm_src   [N,64] fp16, MFMA ----------------
__global__ __launch_bounds__(256) void xw1_mfma_kernel(const void* __restrict__ feats, size_t xoff,
                                                       const void* __restrict__ W1,
                                                       const int* __restrict__ deg_out,
                                                       const int* __restrict__ flag,
                                                       fp16* __restrict__ y1, int N) {
    __shared__ __align__(16) fp16 Wt[HID][IN_DIM + 8];  // [col][k] 17.4 KB
    int isf = *flag;
    int tid = threadIdx.x;
    for (int i = tid; i < IN_DIM * HID; i += 256) {
        int k = i >> 6, c = i & 63;
        Wt[c][k] = (fp16)loadf(W1, i, isf);
    }
    __syncthreads();
    int wave = tid >> 6, lane = tid & 63;
    int lr = lane & 15;        // A row / B col within tile
    int lk = (lane >> 4) * 8;  // k base within k-tile
    f16x8 bfr[4][4];
#pragma unroll
    for (int ct = 0; ct < 4; ++ct)
#pragma unroll
        for (int kt = 0; kt < 4; ++kt)
            bfr[ct][kt] = *(const f16x8*)&Wt[ct * 16 + lr][kt * 32 + lk];
    int tb = blockIdx.x * 64 + wave * 16;
    int rc = min(tb + lr, N - 1);
    f16x8 afr[4];
    if (isf) {
        const float* xr = (const float*)feats + xoff + (size_t)rc * IN_DIM + lk;
#pragma unroll
        for (int kt = 0; kt < 4; ++kt) {
            float4 p0 = *(const float4*)(xr + kt * 32);
            float4 p1 = *(const float4*)(xr + kt * 32 + 4);
            f16x8 a;
            a[0] = (fp16)p0.x; a[1] = (fp16)p0.y; a[2] = (fp16)p0.z; a[3] = (fp16)p0.w;
            a[4] = (fp16)p1.x; a[5] = (fp16)p1.y; a[6] = (fp16)p1.z; a[7] = (fp16)p1.w;
            afr[kt] = a;
        }
    } else {
        const unsigned short* xr = (const unsigned short*)feats + xoff + (size_t)rc * IN_DIM + lk;
#pragma unroll
        for (int kt = 0; kt < 4; ++kt) {
            uint4 q = *(const uint4*)(xr + kt * 32);
            f16x8 a;
            a[0] = (fp16)bf2f((unsigned short)(q.x & 0xffff));
            a[1] = (fp16)bf2f((unsigned short)(q.x >> 16));
            a[2] = (fp16)bf2f((unsigned short)(q.y & 0xffff));
            a[3] = (fp16)bf2f((unsigned short)(q.y >> 16));
            a[4] = (fp16)bf2f((unsigned short)(q.z & 0xffff));
            a[5] = (fp16)bf2f((unsigned short)(q.z >> 16));
            a[6] = (fp16)bf2f((unsigned short)(q.w & 0xffff));
            a[7] = (fp16)bf2f((unsigned short)(q.w >> 16));
            afr[kt] = a;
        }
    }
    f32x4 acc[4] = {};
#pragma unroll
    for (int ct = 0; ct < 4; ++ct)
#pragma unroll
        for (int kt = 0; kt < 4; ++kt)
            acc[ct] = __builtin_amdgcn_mfma_f32_16x16x32_f16(afr[kt], bfr[ct][kt], acc[ct], 0, 0, 0);
    int sr0 = tb + (lane >> 4) * 4;
    int sc = lane & 15;
#pragma unroll
    for (int i = 0; i < 4; ++i) {
        int row = sr0 + i;
        if (row < N) {
            float ns = rsqrtf(fmaxf((float)deg_out[row], 1.f));
#pragma unroll
            for (int ct = 0; ct < 4; ++ct)
                y1[(size_t)row * HID + ct * 16 + sc] = (fp16)(acc[ct][i] * ns);
        }
    }
}

// ---------------- y2 = (h @ W2) * norm_src, MFMA ----------------
__global__ __launch_bounds__(256) void mlp2_mfma_kernel(const fp16* __restrict__ h,
                                                        const void* __restrict__ W2,
                                                        const int* __restrict__ deg_out,
                                                        const int* __restrict__ flag,
                                                        fp16* __restrict__ y2, int N) {
    __shared__ __align__(16) fp16 Wt[HID][HID + 8];  // [col][k] 9.2 KB
    int isf = *flag;
    int tid = threadIdx.x;
    for (int i = tid; i < HID * HID; i += 256) {
        int k = i >> 6, c = i & 63;
        Wt[c][k] = (fp16)loadf(W2, i, isf);
    }
    __syncthreads();
    int wave = tid >> 6, lane = tid & 63;
    int lr = lane & 15, lk = (lane >> 4) * 8;
    f16x8 bfr[4][2];
#pragma unroll
    for (int ct = 0; ct < 4; ++ct)
#pragma unroll
        for (int kt = 0; kt < 2; ++kt)
            bfr[ct][kt] = *(const f16x8*)&Wt[ct * 16 + lr][kt * 32 + lk];
    int tb = blockIdx.x * 64 + wave * 16;
    int rc = min(tb + lr, N - 1);
    f16x8 afr[2];
#pragma unroll
    for (int kt = 0; kt < 2; ++kt)
        afr[kt] = *(const f16x8*)&h[(size_t)rc * HID + kt * 32 + lk];
    f32x4 acc[4] = {};
#pragma unroll
    for (int ct = 0; ct < 4; ++ct)
#pragma unroll
        for (int kt = 0; kt < 2; ++kt)
            acc[ct] = __builtin_amdgcn_mfma_f32_16x16x32_f16(afr[kt], bfr[ct][kt], acc[ct], 0, 0, 0);
    int sr0 = tb + (lane >> 4) * 4;
    int sc = lane & 15;
#pragma unroll
    for (int i = 0; i < 4; ++i) {
        int row = sr0 + i;
        if (row < N) {
            float ns = rsqrtf(fmaxf((float)deg_out[row], 1.f));
#pragma unroll
            for (int ct = 0; ct < 4; ++ct)
                y2[(size_t)row * HID + ct * 16 + sc] = (fp16)(acc[ct][i] * ns);
        }
    }
}

// ---------------- u = h@W3_top, v = h@W3_bot, MFMA ----------------
__global__ __launch_bounds__(256) void mlp3_mfma_kernel(const fp16* __restrict__ h,
                                                        const void* __restrict__ W3,
                                                        const int* __restrict__ flag,
                                                        fp16* __restrict__ u,
                                                        fp16* __restrict__ v, int N) {
    __shared__ __align__(16) fp16 Wt[HID][2 * HID + 8];  // [col][kk 0..127] 17.4 KB
    int isf = *flag;
    int tid = threadIdx.x;
    for (int i = tid; i < 2 * HID * HID; i += 256) {
        int k = i >> 6, c = i & 63;  // k 0..127 (top then bottom half), c = out col
        Wt[c][k] = (fp16)loadf(W3, i, isf);
    }
    __syncthreads();
    int wave = tid >> 6, lane = tid & 63;
    int lr = lane & 15, lk = (lane >> 4) * 8;
    f16x8 bu[4][2], bv[4][2];
#pragma unroll
    for (int ct = 0; ct < 4; ++ct)
#pragma unroll
        for (int kt = 0; kt < 2; ++kt) {
            bu[ct][kt] = *(const f16x8*)&Wt[ct * 16 + lr][kt * 32 + lk];
            bv[ct][kt] = *(const f16x8*)&Wt[ct * 16 + lr][HID + kt * 32 + lk];
        }
    int tb = blockIdx.x * 64 + wave * 16;
    int rc = min(tb + lr, N - 1);
    f16x8 afr[2];
#pragma unroll
    for (int kt = 0; kt < 2; ++kt)
        afr[kt] = *(const f16x8*)&h[(size_t)rc * HID + kt * 32 + lk];
    f32x4 accu[4] = {}, accv[4] = {};
#pragma unroll
    for (int ct = 0; ct < 4; ++ct)
#pragma unroll
        for (int kt = 0; kt < 2; ++kt) {
            accu[ct] = __builtin_amdgcn_mfma_f32_16x16x32_f16(afr[kt], bu[ct][kt], accu[ct], 0, 0, 0);
            accv[ct] = __builtin_amdgcn_mfma_f32_16x16x32_f16(afr[kt], bv[ct][kt], accv[ct], 0, 0, 0);
        }
    int sr0 = tb + (lane >> 4) * 4;
    int sc = lane & 15;
#pragma unroll
    for (int i = 0; i < 4; ++i) {
        int row = sr0 + i;
        if (row < N) {
#pragma unroll
            for (int ct = 0; ct < 4; ++ct) {
                u[(size_t)row * HID + ct * 16 + sc] = (fp16)accu[ct][i];
                v[(size_t)row * HID + ct * 16 + sc] = (fp16)accv[ct][i];
            }
        }
    }
}

// ---------------- pure gather: h[n] = (relu?)(agg(y)*nd + bias) ----------------
// Two nodes per wave: each 32-lane half owns one node, a lane holds a dword
// (2 fp16 feats). 16-deep unroll -> 32 independent 128B row requests in flight
// per wave. Grid-stride over 4096 blocks smooths degree variance.
__global__ __launch_bounds__(256, 4) void gather_kernel(const fp16* __restrict__ y,
                                                        const void* __restrict__ bias,
                                                        const int* __restrict__ row_start,
                                                        const int* __restrict__ csr_src,
                                                        const int* __restrict__ flag,
                                                        fp16* __restrict__ h,
                                                        int N, int do_relu) {
    int isf = *flag;
    int tid = threadIdx.x;
    int wave = tid >> 6, lane = tid & 63;
    int half = lane >> 5, sub = lane & 31;
    float bl0 = loadf(bias, 2 * sub, isf), bl1 = loadf(bias, 2 * sub + 1, isf);
    const int NP = (N + 1) >> 1;  // node pairs
    for (int p = blockIdx.x * 4 + wave; p < NP; p += gridDim.x * 4) {
        int n = min(2 * p + half, N - 1);
        int rs = row_start[n];
        int re = row_start[n + 1];
        float a0 = 0.f, a1 = 0.f;
        for (int base_e = rs; base_e < re; base_e += 16) {
            int sarr[16];
#pragma unroll
            for (int j = 0; j < 16; ++j) {
                int ec = min(base_e + j, re - 1);  // clamp, safe addr
                sarr[j] = csr_src[ec];             // broadcast within half
            }
            unsigned uarr[16];
#pragma unroll
            for (int j = 0; j < 16; ++j)
                uarr[j] = ((const unsigned*)(y + (size_t)sarr[j] * HID))[sub];
#pragma unroll
            for (int j = 0; j < 16; ++j) {
                bool ok = base_e + j < re;
                h2 hh = __builtin_bit_cast(h2, uarr[j]);
                a0 += ok ? (float)hh[0] : 0.f;
                a1 += ok ? (float)hh[1] : 0.f;
            }
        }
        float nd = rsqrtf(fmaxf((float)(re - rs), 1.f));
        float r0 = fmaf(a0, nd, bl0);
        float r1 = fmaf(a1, nd, bl1);
        if (do_relu) { r0 = fmaxf(r0, 0.f); r1 = fmaxf(r1, 0.f); }
        if (2 * p + half < N) {
            h2 rr; rr[0] = (fp16)r0; rr[1] = (fp16)r1;
            ((unsigned*)(h + (size_t)n * HID))[sub] = __builtin_bit_cast(unsigned, rr);
        }
    }
}

// ---------------- per-edge scorer, 2 edges/wave packed, 8 pairs in flight ----
#define SCORE_U 8
__global__ __launch_bounds__(256, 8) void score_kernel(const fp16* __restrict__ u,
                                                       const fp16* __restrict__ v,
                                                       const int* __restrict__ sn,
                                                       const int* __restrict__ dn,
                                                       const void* __restrict__ b3,
                                                       const void* __restrict__ W4,
                                                       const void* __restrict__ b4,
                                                       const int* __restrict__ flag,
                                                       void* __restrict__ out, int E) {
    int isf = *flag;
    int tid = threadIdx.x;
    int lane = tid & 63;
    int half = lane >> 5, sub = lane & 31;
    int gw = (blockIdx.x * 256 + tid) >> 6;  // global wave id
    int nw = gridDim.x * 4;
    float b30 = loadf(b3, 2 * sub, isf), b31 = loadf(b3, 2 * sub + 1, isf);
    float w40 = loadf(W4, 2 * sub, isf), w41 = loadf(W4, 2 * sub + 1, isf);
    float b4v = loadf(b4, 0, isf);
    const int P = (E + 1) >> 1;  // pairs

    int p0 = gw;
    for (; p0 + (SCORE_U - 1) * nw < P - 1; p0 += SCORE_U * nw) {
        int ss[SCORE_U], dd[SCORE_U];
#pragma unroll
        for (int j = 0; j < SCORE_U; ++j) {
            int e = 2 * (p0 + j * nw) + half;
            ss[j] = sn[e];
            dd[j] = dn[e];
        }
        unsigned pu[SCORE_U], pv[SCORE_U];
#pragma unroll
        for (int j = 0; j < SCORE_U; ++j) {
            pu[j] = ((const unsigned*)(u + (size_t)ss[j] * HID))[sub];
            pv[j] = ((const unsigned*)(v + (size_t)dd[j] * HID))[sub];
        }
#pragma unroll
        for (int j = 0; j < SCORE_U; ++j) {
            int e = 2 * (p0 + j * nw) + half;
            h2 hu = __builtin_bit_cast(h2, pu[j]);
            h2 hv = __builtin_bit_cast(h2, pv[j]);
            float h0 = fmaxf((float)hu[0] + (float)hv[0] + b30, 0.f);
            float h1 = fmaxf((float)hu[1] + (float)hv[1] + b31, 0.f);
            float pp = fmaf(h0, w40, h1 * w41);
#pragma unroll
            for (int off = 16; off > 0; off >>= 1) pp += __shfl_xor(pp, off, 64);
            if (sub == 0) {
                float r = pp + b4v;
                if (isf) ((float*)out)[e] = r;
                else     ((bf16*)out)[e] = __float2bfloat16(r);
            }
        }
    }
    // guarded tail
    for (; p0 < P; p0 += nw) {
        int e = 2 * p0 + half;
        int ec = min(e, E - 1);
        int s = sn[ec], d = dn[ec];
        unsigned pu = ((const unsigned*)(u + (size_t)s * HID))[sub];
        unsigned pv = ((const unsigned*)(v + (size_t)d * HID))[sub];
        h2 hu = __builtin_bit_cast(h2, pu);
        h2 hv = __builtin_bit_cast(h2, pv);
        float h0 = fmaxf((float)hu[0] + (float)hv[0] + b30, 0.f);
        float h1 = fmaxf((float)hu[1] + (float)hv[1] + b31, 0.f);
        float pp = fmaf(h0, w40, h1 * w41);
#pragma unroll
        for (int off = 16; off > 0; off >>= 1) pp += __shfl_xor(pp, off, 64);
        if (sub == 0 && e < E) {
            float r = pp + b4v;
            if (isf) ((float*)out)[e] = r;
            else     ((bf16*)out)[e] = __float2bfloat16(r);
        }
    }
}

extern "C" void kernel_launch(void* const* d_in, const int* in_sizes, int n_in,
                              void* d_out, int out_size, void* d_ws, size_t ws_size,
                              hipStream_t stream) {
    const void* feats = d_in[0];
    const void* W1 = d_in[1];
    const void* b1 = d_in[2];
    const void* W2 = d_in[3];
    const void* b2 = d_in[4];
    const void* W3 = d_in[5];
    const void* b3 = d_in[6];
    const void* W4 = d_in[7];
    const void* b4 = d_in[8];
    const int* src_seq = (const int*)d_in[9];
    const int* dst_seq = (const int*)d_in[10];
    const int* src_next = (const int*)d_in[11];
    const int* dst_next = (const int*)d_in[12];

    const int E = in_sizes[11];                // src_next
    const int N = in_sizes[0] / (3 * IN_DIM);  // feats = [T=3, N, 128]
    const int T = in_sizes[9] / E;             // 3

    // only the last snapshot matters: h = h_seq[-1]
    const size_t xoff = (size_t)(T - 1) * N * IN_DIM;  // element offset into feats
    const int* src = src_seq + (size_t)(T - 1) * E;
    const int* dst = dst_seq + (size_t)(T - 1) * E;

    char* w = (char*)d_ws;
    auto alloc = [&](size_t bytes) {
        void* p = (void*)w;
        w += (bytes + 255) & ~(size_t)255;
        return p;
    };
    int* flag      = (int*)alloc(4);
    int* deg_out   = (int*)alloc((size_t)N * 4);
    int* row_start = (int*)alloc((size_t)(N + 1) * 4);
    int* gcursor   = (int*)alloc(512 * 4);
    int* bbase     = (int*)alloc(512 * 4);
    int* csr_src   = (int*)alloc((size_t)E * 4);
    fp16* y1       = (fp16*)alloc((size_t)N * HID * 2);
    fp16* y2       = (fp16*)alloc((size_t)N * HID * 2);
    fp16* vv       = (fp16*)alloc((size_t)N * HID * 2);
    fp16* hbuf     = (fp16*)alloc((size_t)N * HID * 2);
    fp16* uu       = y1;         // y1 dead after gather1; reuse as u
    int* binned    = (int*)y2;   // y2 first written by mlp2 (after csr_build) -> safe alias

    // bucket geometry: 256 dst nodes per bucket
    const int B = (N + 255) >> 8;              // 391 for N=100K (must be <=512)
    int sh = 1;
    while ((1 << sh) < N) ++sh;                // 17 bits for src
    int avg = (E + B - 1) / B;
    int CAP = (avg + avg / 2 + 256 + 15) & ~15;  // ~+50% headroom over mean degree*256
    size_t maxints = (size_t)N * HID * 2 / 4;    // ints available in y2 alias
    if ((size_t)B * CAP > maxints) CAP = (int)(maxints / B) & ~15;
    const int nb = (E + BIN_BS - 1) / BIN_BS;  // 196 batches
    const int GB = (N + 63) / 64;              // per-64-node grids

    init_kernel<<<512, 256, 0, stream>>>((const unsigned short*)feats, flag,
                                         deg_out, N, gcursor, B, CAP);
    // CSR build: bin by dst bucket (direct rank-scatter), then per-bucket build
    bin_kernel<<<nb, 512, 0, stream>>>(src, dst, deg_out, gcursor, binned, E, sh, nb);
    bucket_scan_kernel<<<1, 512, 0, stream>>>(gcursor, bbase, row_start, B, CAP, N);
    csr_build_kernel<<<B, 256, 0, stream>>>(binned, gcursor, bbase, row_start, csr_src,
                                            N, CAP, sh);
    xw1_mfma_kernel<<<GB, 256, 0, stream>>>(feats, xoff, W1, deg_out, flag, y1, N);
    // layer 1: gather (latency-bound, grid-stride) then dense MLP
    gather_kernel<<<4096, 256, 0, stream>>>(y1, b1, row_start, csr_src, flag, hbuf, N, 1);
    mlp2_mfma_kernel<<<GB, 256, 0, stream>>>(hbuf, W2, deg_out, flag, y2, N);
    // layer 2
    gather_kernel<<<4096, 256, 0, stream>>>(y2, b2, row_start, csr_src, flag, hbuf, N, 0);
    mlp3_mfma_kernel<<<GB, 256, 0, stream>>>(hbuf, W3, flag, uu, vv, N);
    score_kernel<<<4096, 256, 0, stream>>>(uu, vv, src_next, dst_next, b3, W4, b4, flag,
                                           (void*)d_out, E);
}

// Round 7
// 527.421 us; speedup vs baseline: 1.0343x; 1.0122x over previous
//
#include <hip/hip_runtime.h>
#include <hip/hip_bf16.h>
#include <hip/hip_fp16.h>

#define IN_DIM 128
#define HID 64
#define BIN_BS 8192   // edges per bin batch (512 threads x 16)
#define BINB 512      // padded bucket-array width (>= B; N<=131072 -> B<=512)

typedef __hip_bfloat16 bf16;
typedef _Float16 fp16;
typedef _Float16 h2 __attribute__((ext_vector_type(2)));
typedef _Float16 f16x8 __attribute__((ext_vector_type(8)));
typedef float f32x4 __attribute__((ext_vector_type(4)));

// generic element load: is_f32 ? fp32 : bf16 (element-indexed)
__device__ __forceinline__ float loadf(const void* p, size_t i, int isf) {
    if (isf) return ((const float*)p)[i];
    unsigned int u = ((const unsigned short*)p)[i];
    union { unsigned int b; float f; } c;
    c.b = u << 16;
    return c.f;
}

__device__ __forceinline__ float bf2f(unsigned short u) {
    union { unsigned int b; float f; } c;
    c.b = ((unsigned int)u) << 16;
    return c.f;
}

// ---------------- init: dtype detect + zero deg_out + bucket cursors ----------------
__global__ void init_kernel(const unsigned short* __restrict__ feats, int* flag,
                            int* __restrict__ deg_out, int N,
                            int* __restrict__ gcursor, int B, int CAP) {
    int i = blockIdx.x * blockDim.x + threadIdx.x;
    int stride = gridDim.x * blockDim.x;
    for (int j = i; j < N; j += stride) deg_out[j] = 0;
    if (i < B) gcursor[i] = i * CAP;
    if (blockIdx.x == 0 && threadIdx.x < 64) {  // wave 0 does the dtype sniff
        int lane = threadIdx.x;
        int bad = 0;
        for (int j = lane; j < 128; j += 64) {
            unsigned short u = feats[j];
            int expo = (u >> 7) & 0xFF;
            if (expo >= 141) bad = 1;
        }
        unsigned long long m = __ballot(bad);
        if (lane == 0) *flag = (__popcll(m) > 4) ? 1 : 0;
    }
}

// ---------------- edge binning by dst bucket (dst>>8), direct rank-scatter ----------
// Intra-bucket order is irrelevant (csr_build re-sorts), so no staging/scan/search:
// count -> one global reservation per non-empty bucket -> atomic-rank scatter.
__global__ __launch_bounds__(512) void bin_kernel(const int* __restrict__ src,
                                                  const int* __restrict__ dst,
                                                  int* __restrict__ deg_out,
                                                  int* __restrict__ gcursor,
                                                  int* __restrict__ binned,
                                                  int E, int sh, int nb) {
    __shared__ int scnt[BINB];    // per-bucket count, then rank counters
    __shared__ int sgbase[BINB];  // per-bucket global base for this batch
    int tid = threadIdx.x;
    for (int batch = blockIdx.x; batch < nb; batch += gridDim.x) {
        int base = batch * BIN_BS;
        scnt[tid] = 0;
        __syncthreads();
        // phase 1: read edges (kept in regs), count buckets, deg_out atomics
        int ent[16], bk[16];
#pragma unroll
        for (int j = 0; j < 16; ++j) {
            int idx = base + tid + j * 512;
            bool ok = idx < E;
            int s = ok ? src[idx] : 0;
            int d = ok ? dst[idx] : 0;
            int b = d >> 8;
            bk[j] = ok ? b : -1;
            ent[j] = ((d & 255) << sh) | s;
            if (ok) {
                atomicAdd(&deg_out[s], 1);
                atomicAdd(&scnt[b], 1);
            }
        }
        __syncthreads();
        // phase 2: one global reservation per non-empty bucket
        int c = scnt[tid];
        if (c > 0) sgbase[tid] = atomicAdd(&gcursor[tid], c);
        __syncthreads();
        scnt[tid] = 0;  // reuse as rank counters
        __syncthreads();
        // phase 3: direct rank scatter
#pragma unroll
        for (int j = 0; j < 16; ++j) {
            int b = bk[j];
            if (b >= 0) {
                int r = atomicAdd(&scnt[b], 1);
                binned[sgbase[b] + r] = ent[j];
            }
        }
        __syncthreads();  // protect scnt before next batch
    }
}

// ---------------- per-bucket CSR build: self-computed base + count/scan/rank scatter ----
// obase computed per block (sum over gcursor[i]-i*CAP, i<b: <=512 L2-hot reads + LDS
// reduce) -- eliminates the separate bucket_scan dispatch.
__global__ __launch_bounds__(256) void csr_build_kernel(const int* __restrict__ binned,
                                                        const int* __restrict__ gcursor,
                                                        int* __restrict__ row_start,
                                                        int* __restrict__ csr_src,
                                                        int N, int B, int CAP, int sh) {
    __shared__ int lcnt[256];
    __shared__ int loff[256];
    __shared__ int red[256];
    int b = blockIdx.x;
    int tid = threadIdx.x;
    int rbase = b * CAP;
    int cnt = gcursor[b] - rbase;
    // obase = sum of counts of buckets < b
    int partial = 0;
    for (int i = tid; i < b; i += 256) partial += gcursor[i] - i * CAP;
    red[tid] = partial;
    lcnt[tid] = 0;
    __syncthreads();
    for (int off = 128; off > 0; off >>= 1) {
        if (tid < off) red[tid] += red[tid + off];
        __syncthreads();
    }
    int obase = red[0];
    if (b == B - 1 && tid == 0) row_start[N] = obase + cnt;  // == E
    int n0 = b << 8;
    int mask = (1 << sh) - 1;
    for (int i = tid; i < cnt; i += 256) {
        int e = binned[rbase + i];
        atomicAdd(&lcnt[e >> sh], 1);
    }
    __syncthreads();
    int c = lcnt[tid];
    lcnt[tid] = 0;  // reset for rank phase
    loff[tid] = c;
    __syncthreads();
    for (int off = 1; off < 256; off <<= 1) {
        int add = (tid >= off) ? loff[tid - off] : 0;
        __syncthreads();
        loff[tid] += add;
        __syncthreads();
    }
    int incl = loff[tid];
    loff[tid] = incl - c;  // exclusive
    if (n0 + tid < N) row_start[n0 + tid] = obase + incl - c;
    __syncthreads();
    for (int i = tid; i < cnt; i += 256) {
        int e = binned[rbase + i];
        int dl = e >> sh;
        int r = atomicAdd(&lcnt[dl], 1);
        csr_src[obase + loff[dl] + r] = e & mask;  // L2-localized scatter
    }
}

// ============ MFMA dense layer kernels ============
// mfma_f32_16x16x32_f16 fragment layouts (per guide, m89/m91-verified C/D):
//   A: lane holds A[row=lane&15][k = (lane>>4)*8 + j], j=0..7 (8 contiguous k)
//   B: lane holds B[k = (lane>>4)*8 + j][col=lane&15]  -> read from W^T, 8 contiguous k
//   C/D: col=lane&15, row=(lane>>4)*4 + reg
// 64 rows per block -> ~1563 blocks (6/CU) so the memory pipes fill.

// ---------------- y1 = (x @ W1) * norm_src   [N,64] fp16, MFMA ----------------
__global__ __launch_bounds__(256) void xw1_mfma_kernel(const void* __restrict__ feats, size_t xoff,
                                                       const void* __restrict__ W1,
                                                       const int* __restrict__ deg_out,
                                                       const int* __restrict__ flag,
                                                       fp16* __restrict__ y1, int N) {
    __shared__ __align__(16) fp16 Wt[HID][IN_DIM + 8];  // [col][k] 17.4 KB
    int isf = *flag;
    int tid = threadIdx.x;
    for (int i = tid; i < IN_DIM * HID; i += 256) {
        int k = i >> 6, c = i & 63;
        Wt[c][k] = (fp16)loadf(W1, i, isf);
    }
    __syncthreads();
    int wave = tid >> 6, lane = tid & 63;
    int lr = lane & 15;        // A row / B col within tile
    int lk = (lane >> 4) * 8;  // k base within k-tile
    f16x8 bfr[4][4];
#pragma unroll
    for (int ct = 0; ct < 4; ++ct)
#pragma unroll
        for (int kt = 0; kt < 4; ++kt)
            bfr[ct][kt] = *(const f16x8*)&Wt[ct * 16 + lr][kt * 32 + lk];
    int tb = blockIdx.x * 64 + wave * 16;
    int rc = min(tb + lr, N - 1);
    f16x8 afr[4];
    if (isf) {
        const float* xr = (const float*)feats + xoff + (size_t)rc * IN_DIM + lk;
#pragma unroll
        for (int kt = 0; kt < 4; ++kt) {
            float4 p0 = *(const float4*)(xr + kt * 32);
            float4 p1 = *(const float4*)(xr + kt * 32 + 4);
            f16x8 a;
            a[0] = (fp16)p0.x; a[1] = (fp16)p0.y; a[2] = (fp16)p0.z; a[3] = (fp16)p0.w;
            a[4] = (fp16)p1.x; a[5] = (fp16)p1.y; a[6] = (fp16)p1.z; a[7] = (fp16)p1.w;
            afr[kt] = a;
        }
    } else {
        const unsigned short* xr = (const unsigned short*)feats + xoff + (size_t)rc * IN_DIM + lk;
#pragma unroll
        for (int kt = 0; kt < 4; ++kt) {
            uint4 q = *(const uint4*)(xr + kt * 32);
            f16x8 a;
            a[0] = (fp16)bf2f((unsigned short)(q.x & 0xffff));
            a[1] = (fp16)bf2f((unsigned short)(q.x >> 16));
            a[2] = (fp16)bf2f((unsigned short)(q.y & 0xffff));
            a[3] = (fp16)bf2f((unsigned short)(q.y >> 16));
            a[4] = (fp16)bf2f((unsigned short)(q.z & 0xffff));
            a[5] = (fp16)bf2f((unsigned short)(q.z >> 16));
            a[6] = (fp16)bf2f((unsigned short)(q.w & 0xffff));
            a[7] = (fp16)bf2f((unsigned short)(q.w >> 16));
            afr[kt] = a;
        }
    }
    f32x4 acc[4] = {};
#pragma unroll
    for (int ct = 0; ct < 4; ++ct)
#pragma unroll
        for (int kt = 0; kt < 4; ++kt)
            acc[ct] = __builtin_amdgcn_mfma_f32_16x16x32_f16(afr[kt], bfr[ct][kt], acc[ct], 0, 0, 0);
    int sr0 = tb + (lane >> 4) * 4;
    int sc = lane & 15;
#pragma unroll
    for (int i = 0; i < 4; ++i) {
        int row = sr0 + i;
        if (row < N) {
            float ns = rsqrtf(fmaxf((float)deg_out[row], 1.f));
#pragma unroll
            for (int ct = 0; ct < 4; ++ct)
                y1[(size_t)row * HID + ct * 16 + sc] = (fp16)(acc[ct][i] * ns);
        }
    }
}

// ---------------- y2 = (h @ W2) * norm_src, MFMA ----------------
__global__ __launch_bounds__(256) void mlp2_mfma_kernel(const fp16* __restrict__ h,
                                                        const void* __restrict__ W2,
                                                        const int* __restrict__ deg_out,
                                                        const int* __restrict__ flag,
                                                        fp16* __restrict__ y2, int N) {
    __shared__ __align__(16) fp16 Wt[HID][HID + 8];  // [col][k] 9.2 KB
    int isf = *flag;
    int tid = threadIdx.x;
    for (int i = tid; i < HID * HID; i += 256) {
        int k = i >> 6, c = i & 63;
        Wt[c][k] = (fp16)loadf(W2, i, isf);
    }
    __syncthreads();
    int wave = tid >> 6, lane = tid & 63;
    int lr = lane & 15, lk = (lane >> 4) * 8;
    f16x8 bfr[4][2];
#pragma unroll
    for (int ct = 0; ct < 4; ++ct)
#pragma unroll
        for (int kt = 0; kt < 2; ++kt)
            bfr[ct][kt] = *(const f16x8*)&Wt[ct * 16 + lr][kt * 32 + lk];
    int tb = blockIdx.x * 64 + wave * 16;
    int rc = min(tb + lr, N - 1);
    f16x8 afr[2];
#pragma unroll
    for (int kt = 0; kt < 2; ++kt)
        afr[kt] = *(const f16x8*)&h[(size_t)rc * HID + kt * 32 + lk];
    f32x4 acc[4] = {};
#pragma unroll
    for (int ct = 0; ct < 4; ++ct)
#pragma unroll
        for (int kt = 0; kt < 2; ++kt)
            acc[ct] = __builtin_amdgcn_mfma_f32_16x16x32_f16(afr[kt], bfr[ct][kt], acc[ct], 0, 0, 0);
    int sr0 = tb + (lane >> 4) * 4;
    int sc = lane & 15;
#pragma unroll
    for (int i = 0; i < 4; ++i) {
        int row = sr0 + i;
        if (row < N) {
            float ns = rsqrtf(fmaxf((float)deg_out[row], 1.f));
#pragma unroll
            for (int ct = 0; ct < 4; ++ct)
                y2[(size_t)row * HID + ct * 16 + sc] = (fp16)(acc[ct][i] * ns);
        }
    }
}

// ---------------- u = h@W3_top, v = h@W3_bot, MFMA ----------------
__global__ __launch_bounds__(256) void mlp3_mfma_kernel(const fp16* __restrict__ h,
                                                        const void* __restrict__ W3,
                                                        const int* __restrict__ flag,
                                                        fp16* __restrict__ u,
                                                        fp16* __restrict__ v, int N) {
    __shared__ __align__(16) fp16 Wt[HID][2 * HID + 8];  // [col][kk 0..127] 17.4 KB
    int isf = *flag;
    int tid = threadIdx.x;
    for (int i = tid; i < 2 * HID * HID; i += 256) {
        int k = i >> 6, c = i & 63;  // k 0..127 (top then bottom half), c = out col
        Wt[c][k] = (fp16)loadf(W3, i, isf);
    }
    __syncthreads();
    int wave = tid >> 6, lane = tid & 63;
    int lr = lane & 15, lk = (lane >> 4) * 8;
    f16x8 bu[4][2], bv[4][2];
#pragma unroll
    for (int ct = 0; ct < 4; ++ct)
#pragma unroll
        for (int kt = 0; kt < 2; ++kt) {
            bu[ct][kt] = *(const f16x8*)&Wt[ct * 16 + lr][kt * 32 + lk];
            bv[ct][kt] = *(const f16x8*)&Wt[ct * 16 + lr][HID + kt * 32 + lk];
        }
    int tb = blockIdx.x * 64 + wave * 16;
    int rc = min(tb + lr, N - 1);
    f16x8 afr[2];
#pragma unroll
    for (int kt = 0; kt < 2; ++kt)
        afr[kt] = *(const f16x8*)&h[(size_t)rc * HID + kt * 32 + lk];
    f32x4 accu[4] = {}, accv[4] = {};
#pragma unroll
    for (int ct = 0; ct < 4; ++ct)
#pragma unroll
        for (int kt = 0; kt < 2; ++kt) {
            accu[ct] = __builtin_amdgcn_mfma_f32_16x16x32_f16(afr[kt], bu[ct][kt], accu[ct], 0, 0, 0);
            accv[ct] = __builtin_amdgcn_mfma_f32_16x16x32_f16(afr[kt], bv[ct][kt], accv[ct], 0, 0, 0);
        }
    int sr0 = tb + (lane >> 4) * 4;
    int sc = lane & 15;
#pragma unroll
    for (int i = 0; i < 4; ++i) {
        int row = sr0 + i;
        if (row < N) {
#pragma unroll
            for (int ct = 0; ct < 4; ++ct) {
                u[(size_t)row * HID + ct * 16 + sc] = (fp16)accu[ct][i];
                v[(size_t)row * HID + ct * 16 + sc] = (fp16)accv[ct][i];
            }
        }
    }
}

// ---------------- pure gather: h[n] = (relu?)(agg(y)*nd + bias) ----------------
// Two nodes per wave (half-wave each, dword/lane), 16-deep -> 32 outstanding
// 128B row requests per wave. min-waves=8: VGPR budget ~55 fits <=64, so 8
// waves/SIMD resident -> 2x outstanding requests vs the (256,4) build.
__global__ __launch_bounds__(256, 8) void gather_kernel(const fp16* __restrict__ y,
                                                        const void* __restrict__ bias,
                                                        const int* __restrict__ row_start,
                                                        const int* __restrict__ csr_src,
                                                        const int* __restrict__ flag,
                                                        fp16* __restrict__ h,
                                                        int N, int do_relu) {
    int isf = *flag;
    int tid = threadIdx.x;
    int wave = tid >> 6, lane = tid & 63;
    int half = lane >> 5, sub = lane & 31;
    float bl0 = loadf(bias, 2 * sub, isf), bl1 = loadf(bias, 2 * sub + 1, isf);
    const int NP = (N + 1) >> 1;  // node pairs
    for (int p = blockIdx.x * 4 + wave; p < NP; p += gridDim.x * 4) {
        int n = min(2 * p + half, N - 1);
        int rs = row_start[n];
        int re = row_start[n + 1];
        float a0 = 0.f, a1 = 0.f;
        for (int base_e = rs; base_e < re; base_e += 16) {
            int sarr[16];
#pragma unroll
            for (int j = 0; j < 16; ++j) {
                int ec = min(base_e + j, re - 1);  // clamp, safe addr
                sarr[j] = csr_src[ec];             // broadcast within half
            }
            unsigned uarr[16];
#pragma unroll
            for (int j = 0; j < 16; ++j)
                uarr[j] = ((const unsigned*)(y + (size_t)sarr[j] * HID))[sub];
#pragma unroll
            for (int j = 0; j < 16; ++j) {
                bool ok = base_e + j < re;
                h2 hh = __builtin_bit_cast(h2, uarr[j]);
                a0 += ok ? (float)hh[0] : 0.f;
                a1 += ok ? (float)hh[1] : 0.f;
            }
        }
        float nd = rsqrtf(fmaxf((float)(re - rs), 1.f));
        float r0 = fmaf(a0, nd, bl0);
        float r1 = fmaf(a1, nd, bl1);
        if (do_relu) { r0 = fmaxf(r0, 0.f); r1 = fmaxf(r1, 0.f); }
        if (2 * p + half < N) {
            h2 rr; rr[0] = (fp16)r0; rr[1] = (fp16)r1;
            ((unsigned*)(h + (size_t)n * HID))[sub] = __builtin_bit_cast(unsigned, rr);
        }
    }
}

// ---------------- per-edge scorer, 2 edges/wave packed, 8 pairs in flight ----
#define SCORE_U 8
__global__ __launch_bounds__(256, 8) void score_kernel(const fp16* __restrict__ u,
                                                       const fp16* __restrict__ v,
                                                       const int* __restrict__ sn,
                                                       const int* __restrict__ dn,
                                                       const void* __restrict__ b3,
                                                       const void* __restrict__ W4,
                                                       const void* __restrict__ b4,
                                                       const int* __restrict__ flag,
                                                       void* __restrict__ out, int E) {
    int isf = *flag;
    int tid = threadIdx.x;
    int lane = tid & 63;
    int half = lane >> 5, sub = lane & 31;
    int gw = (blockIdx.x * 256 + tid) >> 6;  // global wave id
    int nw = gridDim.x * 4;
    float b30 = loadf(b3, 2 * sub, isf), b31 = loadf(b3, 2 * sub + 1, isf);
    float w40 = loadf(W4, 2 * sub, isf), w41 = loadf(W4, 2 * sub + 1, isf);
    float b4v = loadf(b4, 0, isf);
    const int P = (E + 1) >> 1;  // pairs

    int p0 = gw;
    for (; p0 + (SCORE_U - 1) * nw < P - 1; p0 += SCORE_U * nw) {
        int ss[SCORE_U], dd[SCORE_U];
#pragma unroll
        for (int j = 0; j < SCORE_U; ++j) {
            int e = 2 * (p0 + j * nw) + half;
            ss[j] = sn[e];
            dd[j] = dn[e];
        }
        unsigned pu[SCORE_U], pv[SCORE_U];
#pragma unroll
        for (int j = 0; j < SCORE_U; ++j) {
            pu[j] = ((const unsigned*)(u + (size_t)ss[j] * HID))[sub];
            pv[j] = ((const unsigned*)(v + (size_t)dd[j] * HID))[sub];
        }
#pragma unroll
        for (int j = 0; j < SCORE_U; ++j) {
            int e = 2 * (p0 + j * nw) + half;
            h2 hu = __builtin_bit_cast(h2, pu[j]);
            h2 hv = __builtin_bit_cast(h2, pv[j]);
            float h0 = fmaxf((float)hu[0] + (float)hv[0] + b30, 0.f);
            float h1 = fmaxf((float)hu[1] + (float)hv[1] + b31, 0.f);
            float pp = fmaf(h0, w40, h1 * w41);
#pragma unroll
            for (int off = 16; off > 0; off >>= 1) pp += __shfl_xor(pp, off, 64);
            if (sub == 0) {
                float r = pp + b4v;
                if (isf) ((float*)out)[e] = r;
                else     ((bf16*)out)[e] = __float2bfloat16(r);
            }
        }
    }
    // guarded tail
    for (; p0 < P; p0 += nw) {
        int e = 2 * p0 + half;
        int ec = min(e, E - 1);
        int s = sn[ec], d = dn[ec];
        unsigned pu = ((const unsigned*)(u + (size_t)s * HID))[sub];
        unsigned pv = ((const unsigned*)(v + (size_t)d * HID))[sub];
        h2 hu = __builtin_bit_cast(h2, pu);
        h2 hv = __builtin_bit_cast(h2, pv);
        float h0 = fmaxf((float)hu[0] + (float)hv[0] + b30, 0.f);
        float h1 = fmaxf((float)hu[1] + (float)hv[1] + b31, 0.f);
        float pp = fmaf(h0, w40, h1 * w41);
#pragma unroll
        for (int off = 16; off > 0; off >>= 1) pp += __shfl_xor(pp, off, 64);
        if (sub == 0 && e < E) {
            float r = pp + b4v;
            if (isf) ((float*)out)[e] = r;
            else     ((bf16*)out)[e] = __float2bfloat16(r);
        }
    }
}

extern "C" void kernel_launch(void* const* d_in, const int* in_sizes, int n_in,
                              void* d_out, int out_size, void* d_ws, size_t ws_size,
                              hipStream_t stream) {
    const void* feats = d_in[0];
    const void* W1 = d_in[1];
    const void* b1 = d_in[2];
    const void* W2 = d_in[3];
    const void* b2 = d_in[4];
    const void* W3 = d_in[5];
    const void* b3 = d_in[6];
    const void* W4 = d_in[7];
    const void* b4 = d_in[8];
    const int* src_seq = (const int*)d_in[9];
    const int* dst_seq = (const int*)d_in[10];
    const int* src_next = (const int*)d_in[11];
    const int* dst_next = (const int*)d_in[12];

    const int E = in_sizes[11];                // src_next
    const int N = in_sizes[0] / (3 * IN_DIM);  // feats = [T=3, N, 128]
    const int T = in_sizes[9] / E;             // 3

    // only the last snapshot matters: h = h_seq[-1]
    const size_t xoff = (size_t)(T - 1) * N * IN_DIM;  // element offset into feats
    const int* src = src_seq + (size_t)(T - 1) * E;
    const int* dst = dst_seq + (size_t)(T - 1) * E;

    char* w = (char*)d_ws;
    auto alloc = [&](size_t bytes) {
        void* p = (void*)w;
        w += (bytes + 255) & ~(size_t)255;
        return p;
    };
    int* flag      = (int*)alloc(4);
    int* deg_out   = (int*)alloc((size_t)N * 4);
    int* row_start = (int*)alloc((size_t)(N + 1) * 4);
    int* gcursor   = (int*)alloc(512 * 4);
    int* csr_src   = (int*)alloc((size_t)E * 4);
    fp16* y1       = (fp16*)alloc((size_t)N * HID * 2);
    fp16* y2       = (fp16*)alloc((size_t)N * HID * 2);
    fp16* vv       = (fp16*)alloc((size_t)N * HID * 2);
    fp16* hbuf     = (fp16*)alloc((size_t)N * HID * 2);
    fp16* uu       = y1;         // y1 dead after gather1; reuse as u
    int* binned    = (int*)y2;   // y2 first written by mlp2 (after csr_build) -> safe alias

    // bucket geometry: 256 dst nodes per bucket
    const int B = (N + 255) >> 8;              // 391 for N=100K (must be <=512)
    int sh = 1;
    while ((1 << sh) < N) ++sh;                // 17 bits for src
    int avg = (E + B - 1) / B;
    int CAP = (avg + avg / 2 + 256 + 15) & ~15;  // ~+50% headroom over mean degree*256
    size_t maxints = (size_t)N * HID * 2 / 4;    // ints available in y2 alias
    if ((size_t)B * CAP > maxints) CAP = (int)(maxints / B) & ~15;
    const int nb = (E + BIN_BS - 1) / BIN_BS;  // 196 batches
    const int GB = (N + 63) / 64;              // per-64-node grids

    init_kernel<<<512, 256, 0, stream>>>((const unsigned short*)feats, flag,
                                         deg_out, N, gcursor, B, CAP);
    // CSR build: bin by dst bucket (direct rank-scatter), then per-bucket build
    bin_kernel<<<nb, 512, 0, stream>>>(src, dst, deg_out, gcursor, binned, E, sh, nb);
    csr_build_kernel<<<B, 256, 0, stream>>>(binned, gcursor, row_start, csr_src,
                                            N, B, CAP, sh);
    xw1_mfma_kernel<<<GB, 256, 0, stream>>>(feats, xoff, W1, deg_out, flag, y1, N);
    // layer 1: gather (latency-bound, grid-stride) then dense MLP
    gather_kernel<<<4096, 256, 0, stream>>>(y1, b1, row_start, csr_src, flag, hbuf, N, 1);
    mlp2_mfma_kernel<<<GB, 256, 0, stream>>>(hbuf, W2, deg_out, flag, y2, N);
    // layer 2
    gather_kernel<<<4096, 256, 0, stream>>>(y2, b2, row_start, csr_src, flag, hbuf, N, 0);
    mlp3_mfma_kernel<<<GB, 256, 0, stream>>>(hbuf, W3, flag, uu, vv, N);
    score_kernel<<<4096, 256, 0, stream>>>(uu, vv, src_next, dst_next, b3, W4, b4, flag,
                                           (void*)d_out, E);
}